// Round 1
// baseline (124.537 us; speedup 1.0000x reference)
//
#include <hip/hip_runtime.h>
#include <math.h>

#define NB 768
#define ND 128
#define TL_MARGIN 1.0f
#define TL_EPS 1e-12f

// d_ws layout: float psum[NB]; float pcnt[NB];

__global__ __launch_bounds__(256) void triplet_row_kernel(
    const float* __restrict__ E, const int* __restrict__ L,
    float* __restrict__ psum, float* __restrict__ pcnt)
{
    __shared__ float ei[ND];
    __shared__ float drow[NB];
    __shared__ int   lbl[NB];
    __shared__ float redv[256];
    __shared__ int   redi[256];
    __shared__ float reda[256];
    __shared__ float redb[256];

    const int i   = blockIdx.x;
    const int tid = threadIdx.x;

    // stage anchor row + labels into LDS
    if (tid < ND) ei[tid] = E[i * ND + tid];
    for (int j = tid; j < NB; j += 256) lbl[j] = L[j];
    __syncthreads();

    // sq_i (redundant per-thread, cheap)
    float sqi = 0.f;
    #pragma unroll
    for (int k = 0; k < ND; ++k) { float v = ei[k]; sqi += v * v; }

    const int li = lbl[i];

    // each thread computes d[i][j] for j = tid, tid+256, tid+512
    // and tracks local hardest negative (min d over neg, first index wins)
    float bestv = INFINITY;
    int   besti = 0;
    for (int j = tid; j < NB; j += 256) {
        const float4* ej = (const float4*)(E + (size_t)j * ND);
        const float4* ai = (const float4*)ei;
        float dot = 0.f, sqj = 0.f;
        #pragma unroll 8
        for (int k = 0; k < ND / 4; ++k) {
            float4 v = ej[k];
            float4 a = ai[k];
            dot += a.x * v.x + a.y * v.y + a.z * v.z + a.w * v.w;
            sqj += v.x * v.x + v.y * v.y + v.z * v.z + v.w * v.w;
        }
        float d2 = sqi + sqj - 2.f * dot;
        float d  = sqrtf(fmaxf(d2, TL_EPS));
        drow[j] = d;
        if (lbl[j] != li) {
            if (d < bestv) { bestv = d; besti = j; }   // strict <: earliest j kept
        }
    }
    redv[tid] = bestv;
    redi[tid] = besti;
    __syncthreads();

    // block argmin with first-index tie-break (matches jnp.argmin semantics)
    for (int s = 128; s > 0; s >>= 1) {
        if (tid < s) {
            float v2 = redv[tid + s]; int i2 = redi[tid + s];
            float v1 = redv[tid];     int i1 = redi[tid];
            if (v2 < v1 || (v2 == v1 && i2 < i1)) { redv[tid] = v2; redi[tid] = i2; }
        }
        __syncthreads();
    }
    const float hval = redv[0];          // hardest negative distance
    const int   hidx = redi[0];          // (unused value-wise beyond hval, kept for clarity)
    const bool  neg_exists = isfinite(hval);
    (void)hidx;
    __syncthreads();

    // semi-hard mining per positive pair (i, j)
    float lsum = 0.f, lcnt = 0.f;
    if (neg_exists) {
        for (int j = tid; j < NB; j += 256) {
            if (j != i && lbl[j] == li) {
                const float pd = drow[j];
                const float hi = pd + TL_MARGIN;
                float nd = hval;                     // fallback: hardest negative
                for (int k = 0; k < NB; ++k) {       // first k with semi condition
                    if (lbl[k] != li) {
                        float dk = drow[k];
                        if (dk > pd && dk < hi) { nd = dk; break; }
                    }
                }
                lsum += fmaxf(pd - nd + TL_MARGIN, 0.f);
                lcnt += 1.f;
            }
        }
    }
    reda[tid] = lsum;
    redb[tid] = lcnt;
    __syncthreads();
    for (int s = 128; s > 0; s >>= 1) {
        if (tid < s) {
            reda[tid] += reda[tid + s];
            redb[tid] += redb[tid + s];
        }
        __syncthreads();
    }
    if (tid == 0) {
        psum[i] = reda[0];
        pcnt[i] = redb[0];
    }
}

__global__ __launch_bounds__(256) void triplet_finalize_kernel(
    const float* __restrict__ psum, const float* __restrict__ pcnt,
    float* __restrict__ out)
{
    __shared__ float sa[256];
    __shared__ float sb[256];
    const int tid = threadIdx.x;
    float a = 0.f, b = 0.f;
    for (int j = tid; j < NB; j += 256) { a += psum[j]; b += pcnt[j]; }
    sa[tid] = a; sb[tid] = b;
    __syncthreads();
    for (int s = 128; s > 0; s >>= 1) {
        if (tid < s) { sa[tid] += sa[tid + s]; sb[tid] += sb[tid + s]; }
        __syncthreads();
    }
    if (tid == 0) out[0] = sa[0] / fmaxf(sb[0], 1.f);
}

extern "C" void kernel_launch(void* const* d_in, const int* in_sizes, int n_in,
                              void* d_out, int out_size, void* d_ws, size_t ws_size,
                              hipStream_t stream) {
    const float* E = (const float*)d_in[0];
    const int*   L = (const int*)d_in[1];
    float* psum = (float*)d_ws;
    float* pcnt = psum + NB;
    float* out  = (float*)d_out;

    triplet_row_kernel<<<NB, 256, 0, stream>>>(E, L, psum, pcnt);
    triplet_finalize_kernel<<<1, 256, 0, stream>>>(psum, pcnt, out);
}

// Round 2
// 45.793 us; speedup vs baseline: 2.7196x; 2.7196x over previous
//
#include <hip/hip_runtime.h>
#include <math.h>

#define NB 768
#define ND 128
#define NC 12            // NB / 64 lane-chunks
#define TL_MARGIN 1.0f
#define TL_EPS 1e-12f

// d_ws layout: float psum[NB]; float pcnt[NB];

__global__ __launch_bounds__(256) void triplet_row_kernel(
    const float* __restrict__ E, const int* __restrict__ L,
    float* __restrict__ psum, float* __restrict__ pcnt)
{
    __shared__ float ei[ND];
    __shared__ float drow[NB];
    __shared__ int   lbl[NB];
    __shared__ float w_hv[4];
    __shared__ int   w_hi[4];
    __shared__ float w_sum[4];
    __shared__ float w_cnt[4];
    __shared__ float s_hval;

    const int i    = blockIdx.x;
    const int tid  = threadIdx.x;
    const int lane = tid & 63;
    const int wave = tid >> 6;

    if (tid < ND) ei[tid] = E[i * ND + tid];
    for (int j = tid; j < NB; j += 256) lbl[j] = L[j];
    __syncthreads();

    float sqi = 0.f;
    #pragma unroll
    for (int k = 0; k < ND; ++k) { float v = ei[k]; sqi += v * v; }
    const int li = lbl[i];

    // distance row: thread handles j = tid, tid+256, tid+512
    for (int j = tid; j < NB; j += 256) {
        const float4* ej = (const float4*)(E + (size_t)j * ND);
        const float4* ai = (const float4*)ei;
        float dot = 0.f, sqj = 0.f;
        #pragma unroll 8
        for (int k = 0; k < ND / 4; ++k) {
            float4 v = ej[k];
            float4 a = ai[k];
            dot += a.x * v.x + a.y * v.y + a.z * v.z + a.w * v.w;
            sqj += v.x * v.x + v.y * v.y + v.z * v.z + v.w * v.w;
        }
        float d2 = sqi + sqj - 2.f * dot;
        drow[j] = sqrtf(fmaxf(d2, TL_EPS));
    }
    __syncthreads();

    // per-lane register cache of the whole row (static indexing only)
    float dk[NC];
    unsigned negm = 0u, posm = 0u;
    #pragma unroll
    for (int c = 0; c < NC; ++c) {
        int j = c * 64 + lane;
        dk[c] = drow[j];
        int lj = lbl[j];
        if (lj != li)      negm |= (1u << c);
        else if (j != i)   posm |= (1u << c);
    }

    // hardest negative: per-lane min (ascending idx => strict < keeps first),
    // then wave butterfly with first-index tie-break, then 4-wave reduce.
    float bv = INFINITY; int bi = 0x7fffffff;
    #pragma unroll
    for (int c = 0; c < NC; ++c) {
        if ((negm >> c) & 1u) {
            float v = dk[c];
            if (v < bv) { bv = v; bi = c * 64 + lane; }
        }
    }
    #pragma unroll
    for (int off = 32; off > 0; off >>= 1) {
        float ov = __shfl_xor(bv, off);
        int   oi = __shfl_xor(bi, off);
        if (ov < bv || (ov == bv && oi < bi)) { bv = ov; bi = oi; }
    }
    if (lane == 0) { w_hv[wave] = bv; w_hi[wave] = bi; }
    __syncthreads();
    if (tid == 0) {
        float hv = w_hv[0]; int hix = w_hi[0];
        for (int w = 1; w < 4; ++w) {
            float v = w_hv[w]; int idx = w_hi[w];
            if (v < hv || (v == hv && idx < hix)) { hv = v; hix = idx; }
        }
        s_hval = hv;
    }
    __syncthreads();
    const float hval = s_hval;

    // wave-parallel semi-hard mining: wave w owns chunks [3w, 3w+3)
    float lsum = 0.f, lcnt = 0.f;
    if (isfinite(hval)) {
        for (int cc = 0; cc < 3; ++cc) {
            const int c = wave * 3 + cc;
            unsigned long long pm = __ballot((posm >> c) & 1u);
            while (pm) {
                const int sl = __builtin_ctzll(pm);
                pm &= pm - 1;
                const float pd = drow[c * 64 + sl];   // LDS broadcast (uniform addr)
                float nd = hval;                      // fallback: hardest negative
                #pragma unroll
                for (int c2 = 0; c2 < NC; ++c2) {
                    bool pred = ((negm >> c2) & 1u) &&
                                (dk[c2] > pd) && (dk[c2] < pd + TL_MARGIN);
                    unsigned long long m = __ballot(pred);
                    if (m) {                          // first k = first chunk, first lane
                        nd = drow[c2 * 64 + __builtin_ctzll(m)];
                        break;
                    }
                }
                lsum += fmaxf(pd - nd + TL_MARGIN, 0.f);
                lcnt += 1.f;
            }
        }
    }
    if (lane == 0) { w_sum[wave] = lsum; w_cnt[wave] = lcnt; }
    __syncthreads();
    if (tid == 0) {
        psum[i] = w_sum[0] + w_sum[1] + w_sum[2] + w_sum[3];
        pcnt[i] = w_cnt[0] + w_cnt[1] + w_cnt[2] + w_cnt[3];
    }
}

__global__ __launch_bounds__(256) void triplet_finalize_kernel(
    const float* __restrict__ psum, const float* __restrict__ pcnt,
    float* __restrict__ out)
{
    __shared__ float sa[256];
    __shared__ float sb[256];
    const int tid = threadIdx.x;
    float a = 0.f, b = 0.f;
    for (int j = tid; j < NB; j += 256) { a += psum[j]; b += pcnt[j]; }
    sa[tid] = a; sb[tid] = b;
    __syncthreads();
    for (int s = 128; s > 0; s >>= 1) {
        if (tid < s) { sa[tid] += sa[tid + s]; sb[tid] += sb[tid + s]; }
        __syncthreads();
    }
    if (tid == 0) out[0] = sa[0] / fmaxf(sb[0], 1.f);
}

extern "C" void kernel_launch(void* const* d_in, const int* in_sizes, int n_in,
                              void* d_out, int out_size, void* d_ws, size_t ws_size,
                              hipStream_t stream) {
    const float* E = (const float*)d_in[0];
    const int*   L = (const int*)d_in[1];
    float* psum = (float*)d_ws;
    float* pcnt = psum + NB;
    float* out  = (float*)d_out;

    triplet_row_kernel<<<NB, 256, 0, stream>>>(E, L, psum, pcnt);
    triplet_finalize_kernel<<<1, 256, 0, stream>>>(psum, pcnt, out);
}

// Round 3
// 33.408 us; speedup vs baseline: 3.7277x; 1.3707x over previous
//
#include <hip/hip_runtime.h>
#include <math.h>

#define NB 768
#define ND 128
#define NC 12            // NB / 64 lane-chunks
#define APB 4            // anchors per block (= waves per block)
#define TL_MARGIN 1.0f
#define TL_EPS 1e-12f

// d_ws layout: float psum[NB]; float pcnt[NB];

__global__ __launch_bounds__(256) void triplet_batch_kernel(
    const float* __restrict__ E, const int* __restrict__ L,
    float* __restrict__ psum, float* __restrict__ pcnt)
{
    __shared__ float arow[APB][ND];     // 2 KB
    __shared__ float drows[APB][NB];    // 12 KB
    __shared__ int   lbl[NB];           // 3 KB
    __shared__ float s_sqi[APB];

    const int i0   = blockIdx.x * APB;
    const int tid  = threadIdx.x;
    const int lane = tid & 63;
    const int wave = tid >> 6;

    // stage labels + the 4 anchor rows
    for (int j = tid; j < NB; j += 256) lbl[j] = L[j];
    for (int idx = tid; idx < APB * ND; idx += 256) {
        int a = idx >> 7, k = idx & 127;
        arow[a][k] = E[(size_t)(i0 + a) * ND + k];
    }
    __syncthreads();

    // wave w computes sq(anchor w) via shuffle reduce
    {
        float v0 = arow[wave][lane];
        float v1 = arow[wave][lane + 64];
        float s = v0 * v0 + v1 * v1;
        #pragma unroll
        for (int off = 32; off > 0; off >>= 1) s += __shfl_xor(s, off);
        if (lane == 0) s_sqi[wave] = s;
    }
    __syncthreads();
    const float sq0 = s_sqi[0], sq1 = s_sqi[1], sq2 = s_sqi[2], sq3 = s_sqi[3];

    // distance rows for all 4 anchors; each loaded E-row feeds 4 dots
    for (int j = tid; j < NB; j += 256) {
        const float4* ej = (const float4*)(E + (size_t)j * ND);
        const float4* a0p = (const float4*)arow[0];
        const float4* a1p = (const float4*)arow[1];
        const float4* a2p = (const float4*)arow[2];
        const float4* a3p = (const float4*)arow[3];
        float d0 = 0.f, d1 = 0.f, d2 = 0.f, d3 = 0.f, sj = 0.f;
        #pragma unroll 8
        for (int k = 0; k < ND / 4; ++k) {
            float4 v  = ej[k];
            float4 a0 = a0p[k], a1 = a1p[k], a2 = a2p[k], a3 = a3p[k];
            sj += v.x * v.x + v.y * v.y + v.z * v.z + v.w * v.w;
            d0 += a0.x * v.x + a0.y * v.y + a0.z * v.z + a0.w * v.w;
            d1 += a1.x * v.x + a1.y * v.y + a1.z * v.z + a1.w * v.w;
            d2 += a2.x * v.x + a2.y * v.y + a2.z * v.z + a2.w * v.w;
            d3 += a3.x * v.x + a3.y * v.y + a3.z * v.z + a3.w * v.w;
        }
        drows[0][j] = sqrtf(fmaxf(sq0 + sj - 2.f * d0, TL_EPS));
        drows[1][j] = sqrtf(fmaxf(sq1 + sj - 2.f * d1, TL_EPS));
        drows[2][j] = sqrtf(fmaxf(sq2 + sj - 2.f * d2, TL_EPS));
        drows[3][j] = sqrtf(fmaxf(sq3 + sj - 2.f * d3, TL_EPS));
    }
    __syncthreads();

    // wave w mines anchor i0+w, fully wave-local (row cached in registers)
    const int a  = wave;
    const int ia = i0 + a;
    const int li = lbl[ia];

    float dk[NC];
    unsigned negm = 0u, posm = 0u;
    #pragma unroll
    for (int c = 0; c < NC; ++c) {
        int j = c * 64 + lane;
        dk[c] = drows[a][j];
        int lj = lbl[j];
        if (lj != li)    negm |= (1u << c);
        else if (j != ia) posm |= (1u << c);
    }

    // hardest-negative VALUE (argmin ties give identical value, so min suffices)
    float bv = INFINITY;
    #pragma unroll
    for (int c = 0; c < NC; ++c)
        if ((negm >> c) & 1u) bv = fminf(bv, dk[c]);
    #pragma unroll
    for (int off = 32; off > 0; off >>= 1)
        bv = fminf(bv, __shfl_xor(bv, off));
    const float hval = bv;   // uniform across wave

    // semi-hard mining: first k with (neg && pd < dk < pd+margin), else hval
    float lsum = 0.f, lcnt = 0.f;
    if (isfinite(hval)) {
        #pragma unroll 1
        for (int c = 0; c < NC; ++c) {
            unsigned long long pm = __ballot((posm >> c) & 1u);
            while (pm) {
                const int sl = __builtin_ctzll(pm);
                pm &= pm - 1;
                const float pd = __shfl(dk[c], sl);
                float nd = hval;
                #pragma unroll 1
                for (int c2 = 0; c2 < NC; ++c2) {
                    bool pred = ((negm >> c2) & 1u) &&
                                (dk[c2] > pd) && (dk[c2] < pd + TL_MARGIN);
                    unsigned long long m = __ballot(pred);
                    if (m) { nd = __shfl(dk[c2], __builtin_ctzll(m)); break; }
                }
                lsum += fmaxf(pd - nd + TL_MARGIN, 0.f);
                lcnt += 1.f;
            }
        }
    }
    if (lane == 0) { psum[ia] = lsum; pcnt[ia] = lcnt; }
}

__global__ __launch_bounds__(256) void triplet_finalize_kernel(
    const float* __restrict__ psum, const float* __restrict__ pcnt,
    float* __restrict__ out)
{
    __shared__ float sa[256];
    __shared__ float sb[256];
    const int tid = threadIdx.x;
    float a = 0.f, b = 0.f;
    for (int j = tid; j < NB; j += 256) { a += psum[j]; b += pcnt[j]; }
    sa[tid] = a; sb[tid] = b;
    __syncthreads();
    for (int s = 128; s > 0; s >>= 1) {
        if (tid < s) { sa[tid] += sa[tid + s]; sb[tid] += sb[tid + s]; }
        __syncthreads();
    }
    if (tid == 0) out[0] = sa[0] / fmaxf(sb[0], 1.f);
}

extern "C" void kernel_launch(void* const* d_in, const int* in_sizes, int n_in,
                              void* d_out, int out_size, void* d_ws, size_t ws_size,
                              hipStream_t stream) {
    const float* E = (const float*)d_in[0];
    const int*   L = (const int*)d_in[1];
    float* psum = (float*)d_ws;
    float* pcnt = psum + NB;
    float* out  = (float*)d_out;

    triplet_batch_kernel<<<NB / APB, 256, 0, stream>>>(E, L, psum, pcnt);
    triplet_finalize_kernel<<<1, 256, 0, stream>>>(psum, pcnt, out);
}